// Round 9
// baseline (980.855 us; speedup 1.0000x reference)
//
#include <hip/hip_runtime.h>

#define S_   4096
#define H_   1024
#define NH_  16
#define NT_  64                            // 64-key tiles
#define SCALE_LOG2E 0.18033688011112042f   // (1/8) * log2(e)

typedef __attribute__((ext_vector_type(8)))  short short8;
typedef __attribute__((ext_vector_type(16))) float f32x16;

__device__ __forceinline__ unsigned short f2bf(float x) {
    union { float f; unsigned u; } c; c.f = x;
    unsigned r = c.u + 0x7fffu + ((c.u >> 16) & 1u);   // RNE
    return (unsigned short)(r >> 16);
}
__device__ __forceinline__ unsigned pk2(float a, float b) {
    return (unsigned)f2bf(a) | ((unsigned)f2bf(b) << 16);
}
__device__ __forceinline__ unsigned pkt(float a, float b) {
    union { float f; unsigned u; } ca, cb; ca.f = a; cb.f = b;
    return __builtin_amdgcn_perm(cb.u, ca.u, 0x07060302u);  // [bf(b) : bf(a)]
}

// ---------------------------------------------------------------------------
// Prepass: fragment-major bf16 tile images, 4096 u16 per (hd,kt):
//   K''[kc][key][8] : kc = d>>3   (linear = kc*512 + key*8 + e)
//   V''[kc][d][8]   : kc = key>>3 (linear = kc*512 + d*8 + e)
// LDS transpose staging so BOTH sides are contiguous. (passing, round 5)
// ---------------------------------------------------------------------------
__global__ __launch_bounds__(256) void prepack(
    const float* __restrict__ k, const float* __restrict__ v,
    unsigned short* __restrict__ kp, unsigned short* __restrict__ vtp)
{
    __shared__ unsigned sK[64 * 33];
    __shared__ unsigned sV[64 * 33];

    const int t  = threadIdx.x;
    const int kt = blockIdx.x, hd = blockIdx.y;
    const size_t tb = ((size_t)hd * NT_ + kt) * 4096;
    uint4* gk = (uint4*)(kp + tb);
    uint4* gv = (uint4*)(vtp + tb);

    #pragma unroll
    for (int i = 0; i < 4; ++i) {
        int n   = t + 256 * i;
        int row = n >> 4, c4 = n & 15;
        size_t off = (size_t)(kt * 64 + row) * H_ + hd * 64 + c4 * 4;
        {
            float4 a = *(const float4*)(k + off);
            sK[row * 33 + c4 * 2]     = pk2(a.x, a.y);
            sK[row * 33 + c4 * 2 + 1] = pk2(a.z, a.w);
        }
        {
            float4 a = *(const float4*)(v + off);
            sV[row * 33 + c4 * 2]     = pk2(a.x, a.y);
            sV[row * 33 + c4 * 2 + 1] = pk2(a.z, a.w);
        }
    }
    __syncthreads();

    #pragma unroll
    for (int i = 0; i < 2; ++i) {
        int o = t + 256 * i;
        {   // K''
            int kc = o >> 6, key = o & 63;
            uint4 w;
            w.x = sK[key * 33 + kc * 4];
            w.y = sK[key * 33 + kc * 4 + 1];
            w.z = sK[key * 33 + kc * 4 + 2];
            w.w = sK[key * 33 + kc * 4 + 3];
            gk[o] = w;
        }
        {   // V''
            int kc = o >> 6, d = o & 63;
            int dp = d >> 1, sh = (d & 1) * 16;
            unsigned q[8];
            #pragma unroll
            for (int e = 0; e < 8; ++e)
                q[e] = (sV[(kc * 8 + e) * 33 + dp] >> sh) & 0xffffu;
            uint4 w;
            w.x = q[0] | (q[1] << 16);
            w.y = q[2] | (q[3] << 16);
            w.z = q[4] | (q[5] << 16);
            w.w = q[6] | (q[7] << 16);
            gv[o] = w;
        }
    }
}

// === shared inner-loop macros (identical math in both attn kernels) ========
#define LOADF_(KF, VF, tile)                                                 \
    {                                                                        \
        const unsigned short* kt_ = pK + (size_t)(tile) * 4096;              \
        const unsigned short* vt_ = pV + (size_t)(tile) * 4096;              \
        KF[0] = *(const short8*)(kt_);                                       \
        KF[1] = *(const short8*)(kt_ + 1024);                                \
        KF[2] = *(const short8*)(kt_ + 2048);                                \
        KF[3] = *(const short8*)(kt_ + 3072);                                \
        VF[0] = *(const short8*)(vt_);                                       \
        VF[1] = *(const short8*)(vt_ + 256);                                 \
        VF[2] = *(const short8*)(vt_ + 1024);                                \
        VF[3] = *(const short8*)(vt_ + 1280);                                \
    }

#define SMAX_(ST, LS, PU)                                                    \
    {                                                                        \
        _Pragma("unroll")                                                    \
        for (int i2_ = 0; i2_ < 8; ++i2_) {                                  \
            float p0 = __builtin_amdgcn_exp2f(ST[2 * i2_]);                  \
            float p1 = __builtin_amdgcn_exp2f(ST[2 * i2_ + 1]);              \
            LS.x += p0; LS.y += p1;                                          \
            PU[i2_] = pkt(p0, p1);                                           \
        }                                                                    \
    }

#define PVAC_(PU, VF, OA)                                                    \
    {                                                                        \
        _Pragma("unroll")                                                    \
        for (int c_ = 0; c_ < 2; ++c_) {                                     \
            unsigned a0 = PU[4 * c_],     b0 = PU[4 * c_ + 2];               \
            unsigned a1 = PU[4 * c_ + 1], b1 = PU[4 * c_ + 3];               \
            asm("v_permlane32_swap_b32 %0, %1" : "+v"(a0), "+v"(b0));        \
            asm("v_permlane32_swap_b32 %0, %1" : "+v"(a1), "+v"(b1));        \
            union { short8 v; unsigned u[4]; } pf;                           \
            pf.u[0] = a0; pf.u[1] = a1; pf.u[2] = b0; pf.u[3] = b1;          \
            OA[0] = __builtin_amdgcn_mfma_f32_32x32x16_bf16(pf.v, VF[2 * c_],     OA[0], 0, 0, 0); \
            OA[1] = __builtin_amdgcn_mfma_f32_32x32x16_bf16(pf.v, VF[2 * c_ + 1], OA[1], 0, 0, 0); \
        }                                                                    \
    }

#define COMPUTE_(KF, VF)                                                     \
    {                                                                        \
        f32x16 st0 = __builtin_amdgcn_mfma_f32_32x32x16_bf16(KF[0], qf[0][0], zero16, 0, 0, 0); \
        f32x16 st1 = __builtin_amdgcn_mfma_f32_32x32x16_bf16(KF[0], qf[1][0], zero16, 0, 0, 0); \
        st0 = __builtin_amdgcn_mfma_f32_32x32x16_bf16(KF[1], qf[0][1], st0, 0, 0, 0); \
        st1 = __builtin_amdgcn_mfma_f32_32x32x16_bf16(KF[1], qf[1][1], st1, 0, 0, 0); \
        st0 = __builtin_amdgcn_mfma_f32_32x32x16_bf16(KF[2], qf[0][2], st0, 0, 0, 0); \
        st1 = __builtin_amdgcn_mfma_f32_32x32x16_bf16(KF[2], qf[1][2], st1, 0, 0, 0); \
        st0 = __builtin_amdgcn_mfma_f32_32x32x16_bf16(KF[3], qf[0][3], st0, 0, 0, 0); \
        st1 = __builtin_amdgcn_mfma_f32_32x32x16_bf16(KF[3], qf[1][3], st1, 0, 0, 0); \
        unsigned pu0[8], pu1[8];                                             \
        SMAX_(st0, ls[0], pu0);                                              \
        PVAC_(pu0, VF, Oacc[0]);                                             \
        SMAX_(st1, ls[1], pu1);                                              \
        PVAC_(pu1, VF, Oacc[1]);                                             \
    }

#define QPROLOGUE_(ROWBASE)                                                  \
    short8 qf[2][4];                                                         \
    _Pragma("unroll")                                                        \
    for (int s = 0; s < 2; ++s) {                                            \
        const float* qb = q + (size_t)((ROWBASE) + s * 32 + l31) * H_ + hd * 64 + lhi * 8; \
        _Pragma("unroll")                                                    \
        for (int c = 0; c < 4; ++c) {                                        \
            float4 a  = *(const float4*)(qb + c * 16);                       \
            float4 bb = *(const float4*)(qb + c * 16 + 4);                   \
            union { short8 v; unsigned u[4]; } f;                            \
            f.u[0] = pk2(a.x * SCALE_LOG2E, a.y * SCALE_LOG2E);              \
            f.u[1] = pk2(a.z * SCALE_LOG2E, a.w * SCALE_LOG2E);              \
            f.u[2] = pk2(bb.x * SCALE_LOG2E, bb.y * SCALE_LOG2E);            \
            f.u[3] = pk2(bb.z * SCALE_LOG2E, bb.w * SCALE_LOG2E);            \
            qf[s][c] = f.v;                                                  \
        }                                                                    \
    }

#define ACCINIT_                                                             \
    f32x16 Oacc[2][2];                                                       \
    _Pragma("unroll")                                                        \
    for (int s = 0; s < 2; ++s)                                              \
        _Pragma("unroll")                                                    \
        for (int h = 0; h < 2; ++h)                                          \
            _Pragma("unroll")                                                \
            for (int r = 0; r < 16; ++r) Oacc[s][h][r] = 0.0f;               \
    float2 ls[2];                                                            \
    ls[0].x = 0.0f; ls[0].y = 0.0f; ls[1].x = 0.0f; ls[1].y = 0.0f;          \
    f32x16 zero16;                                                           \
    _Pragma("unroll")                                                        \
    for (int r = 0; r < 16; ++r) zero16[r] = 0.0f;

// ---------------------------------------------------------------------------
// FAST PATH: global split-K. 1024 blocks (hf, qt, hd) x 256 thr = 4 blk/CU,
// 4 waves/SIMD. Exact round-5 inner loop over tiles hf*32..hf*32+31.
// hf=0 partial -> o0 (the OUT buffer, unnormalized); hf=1 -> o1 (workspace).
// Deterministic: each partial element written exactly once.
// ---------------------------------------------------------------------------
__global__ __launch_bounds__(256, 4) void attn_partial(
    const float* __restrict__ q,
    const unsigned short* __restrict__ kp,
    const unsigned short* __restrict__ vtp,
    float* __restrict__ o0, float* __restrict__ o1,
    float* __restrict__ lpart)     // [2][16][4096]
{
    __shared__ __align__(16) float sO[4 * 2048];
    __shared__ float sL[2 * 128];

    const int t   = threadIdx.x;
    const int b   = blockIdx.x;
    const int hf  = b >> 9;
    const int b9  = b & 511;
    const int xcd = b9 & 7;
    const int bi  = b9 >> 3;
    const int hd  = xcd * 2 + (bi >> 5);
    const int qt  = bi & 31;

    const int w    = t >> 6;
    const int lane = t & 63;
    const int l31  = lane & 31;
    const int lhi  = lane >> 5;
    const int qg   = w >> 1;
    const int kh   = w & 1;

    const unsigned short* gK = kp  + (size_t)hd * NT_ * 4096;
    const unsigned short* gV = vtp + (size_t)hd * NT_ * 4096;

    QPROLOGUE_(qt * 128 + qg * 64)
    ACCINIT_

    const int kOff = (kh * 32 + l31) * 8 + lhi * 512;
    const int vOff = l31 * 8 + (kh * 4 + lhi) * 512;
    const unsigned short* pK = gK + kOff;
    const unsigned short* pV = gV + vOff;

    short8 kfA[4], vfA[4], kfB[4], vfB[4];

    const int tb = hf * 32;
    LOADF_(kfA, vfA, tb + 0);
    for (int kt2 = 0; kt2 < 15; ++kt2) {
        LOADF_(kfB, vfB, tb + 2 * kt2 + 1);
        COMPUTE_(kfA, vfA);
        LOADF_(kfA, vfA, tb + 2 * kt2 + 2);
        COMPUTE_(kfB, vfB);
    }
    LOADF_(kfB, vfB, tb + 31);
    COMPUTE_(kfA, vfA);
    COMPUTE_(kfB, vfB);

    // ---- epilogue: in-block kh-combine; write UNNORMALIZED partials ----
    #pragma unroll
    for (int s = 0; s < 2; ++s) {
        float lsum = ls[s].x + ls[s].y;
        lsum += __shfl_xor(lsum, 32);
        if (lhi == 0) sL[kh * 128 + qg * 64 + s * 32 + l31] = lsum;
    }
    if (kh == 1) {
        #pragma unroll
        for (int s = 0; s < 2; ++s) {
            float* o = sO + (qg * 2 + s) * 2048;
            #pragma unroll
            for (int h = 0; h < 2; ++h)
                #pragma unroll
                for (int r = 0; r < 16; ++r)
                    o[h * 1024 + r * 64 + lane] = Oacc[s][h][r];
        }
    }
    __syncthreads();
    if (kh == 0) {
        float* op = hf ? o1 : o0;
        #pragma unroll
        for (int s = 0; s < 2; ++s) {
            float lsm[4][4];
            #pragma unroll
            for (int qd = 0; qd < 4; ++qd) {
                int base = qg * 64 + s * 32 + 8 * qd + 4 * lhi;
                float4 a  = *(const float4*)(sL + base);
                float4 bb = *(const float4*)(sL + 128 + base);
                lsm[qd][0] = a.x + bb.x;
                lsm[qd][1] = a.y + bb.y;
                lsm[qd][2] = a.z + bb.z;
                lsm[qd][3] = a.w + bb.w;
            }
            if (l31 == 0) {
                #pragma unroll
                for (int qd = 0; qd < 4; ++qd) {
                    float4 wv; wv.x = lsm[qd][0]; wv.y = lsm[qd][1];
                    wv.z = lsm[qd][2]; wv.w = lsm[qd][3];
                    *(float4*)(lpart + (size_t)hf * (NH_ * S_) + hd * S_
                               + qt * 128 + qg * 64 + s * 32 + 8 * qd + 4 * lhi) = wv;
                }
            }
            const float* o = sO + (qg * 2 + s) * 2048;
            #pragma unroll
            for (int h = 0; h < 2; ++h)
                #pragma unroll
                for (int qd = 0; qd < 4; ++qd)
                    #pragma unroll
                    for (int e = 0; e < 4; ++e) {
                        int r   = 4 * qd + e;
                        int row = e + 8 * qd + 4 * lhi;
                        float val = Oacc[s][h][r] + o[h * 1024 + r * 64 + lane];
                        op[(size_t)(qt * 128 + qg * 64 + s * 32 + row) * H_ + hd * 64 + h * 32 + l31] = val;
                    }
        }
    }
}

// out = (out + O1) * rcp(l0 + l1) — in place, each thread owns its element.
__global__ __launch_bounds__(256) void combine(
    const float* __restrict__ opart1, const float* __restrict__ lpart,
    float* __restrict__ out)
{
    const float4* O1 = (const float4*)opart1;
    float4* Ov = (float4*)out;
    int tid = blockIdx.x * 256 + threadIdx.x;
    #pragma unroll
    for (int it = 0; it < 2; ++it) {
        int i = tid + it * 524288;
        int row_g = i >> 8;
        int hd    = (i & 255) >> 4;
        float l0 = lpart[hd * S_ + row_g];
        float l1 = lpart[NH_ * S_ + hd * S_ + row_g];
        float rinv = __builtin_amdgcn_rcpf(l0 + l1);
        float4 a = Ov[i], bq = O1[i];
        float4 wv;
        wv.x = (a.x + bq.x) * rinv;
        wv.y = (a.y + bq.y) * rinv;
        wv.z = (a.z + bq.z) * rinv;
        wv.w = (a.w + bq.w) * rinv;
        Ov[i] = wv;
    }
}

// ---------------------------------------------------------------------------
// FALLBACK: exact round-5 attn_main (passing, 78.9us). Used when ws_size
// is too small for the split-K partials.
// ---------------------------------------------------------------------------
__global__ __launch_bounds__(256, 2) void attn_main(
    const float* __restrict__ q,
    const unsigned short* __restrict__ kp,
    const unsigned short* __restrict__ vtp,
    float* __restrict__ out)
{
    __shared__ __align__(16) float sO[4 * 2048];
    __shared__ float sL[2 * 128];

    const int t   = threadIdx.x;
    const int b   = blockIdx.x;
    const int xcd = b & 7;
    const int bi  = b >> 3;
    const int hd  = xcd * 2 + (bi >> 5);
    const int qt  = bi & 31;

    const int w    = t >> 6;
    const int lane = t & 63;
    const int l31  = lane & 31;
    const int lhi  = lane >> 5;
    const int qg   = w >> 1;
    const int kh   = w & 1;

    const unsigned short* gK = kp  + (size_t)hd * NT_ * 4096;
    const unsigned short* gV = vtp + (size_t)hd * NT_ * 4096;

    QPROLOGUE_(qt * 128 + qg * 64)
    ACCINIT_

    const int kOff = (kh * 32 + l31) * 8 + lhi * 512;
    const int vOff = l31 * 8 + (kh * 4 + lhi) * 512;
    const unsigned short* pK = gK + kOff;
    const unsigned short* pV = gV + vOff;

    short8 kfA[4], vfA[4], kfB[4], vfB[4];

    LOADF_(kfA, vfA, 0);
    for (int kt2 = 0; kt2 < 31; ++kt2) {
        LOADF_(kfB, vfB, 2 * kt2 + 1);
        COMPUTE_(kfA, vfA);
        LOADF_(kfA, vfA, 2 * kt2 + 2);
        COMPUTE_(kfB, vfB);
    }
    LOADF_(kfB, vfB, 63);
    COMPUTE_(kfA, vfA);
    COMPUTE_(kfB, vfB);

    #pragma unroll
    for (int s = 0; s < 2; ++s) {
        float lsum = ls[s].x + ls[s].y;
        lsum += __shfl_xor(lsum, 32);
        if (lhi == 0) sL[kh * 128 + qg * 64 + s * 32 + l31] = lsum;
    }
    if (kh == 1) {
        #pragma unroll
        for (int s = 0; s < 2; ++s) {
            float* o = sO + (qg * 2 + s) * 2048;
            #pragma unroll
            for (int h = 0; h < 2; ++h)
                #pragma unroll
                for (int r = 0; r < 16; ++r)
                    o[h * 1024 + r * 64 + lane] = Oacc[s][h][r];
        }
    }
    __syncthreads();
    if (kh == 0) {
        #pragma unroll
        for (int s = 0; s < 2; ++s) {
            float linv[4][4];
            #pragma unroll
            for (int qd = 0; qd < 4; ++qd) {
                int base = qg * 64 + s * 32 + 8 * qd + 4 * lhi;
                float4 a  = *(const float4*)(sL + base);
                float4 bb = *(const float4*)(sL + 128 + base);
                linv[qd][0] = __builtin_amdgcn_rcpf(a.x + bb.x);
                linv[qd][1] = __builtin_amdgcn_rcpf(a.y + bb.y);
                linv[qd][2] = __builtin_amdgcn_rcpf(a.z + bb.z);
                linv[qd][3] = __builtin_amdgcn_rcpf(a.w + bb.w);
            }
            const float* o = sO + (qg * 2 + s) * 2048;
            #pragma unroll
            for (int h = 0; h < 2; ++h)
                #pragma unroll
                for (int qd = 0; qd < 4; ++qd)
                    #pragma unroll
                    for (int e = 0; e < 4; ++e) {
                        int r   = 4 * qd + e;
                        int row = e + 8 * qd + 4 * lhi;
                        float val = (Oacc[s][h][r] + o[h * 1024 + r * 64 + lane]) * linv[qd][e];
                        out[(size_t)(qt * 128 + qg * 64 + s * 32 + row) * H_ + hd * 64 + h * 32 + l31] = val;
                    }
        }
    }
}

extern "C" void kernel_launch(void* const* d_in, const int* in_sizes, int n_in,
                              void* d_out, int out_size, void* d_ws, size_t ws_size,
                              hipStream_t stream) {
    const float* q = (const float*)d_in[0];
    const float* k = (const float*)d_in[1];
    const float* v = (const float*)d_in[2];
    float* out = (float*)d_out;

    unsigned short* kp  = (unsigned short*)d_ws;                 // [0, 8MB)
    unsigned short* vtp = kp + (size_t)NH_ * NT_ * 4096;         // [8MB, 16MB)

    prepack<<<dim3(NT_, NH_), 256, 0, stream>>>(k, v, kp, vtp);

    const size_t need = (size_t)32 * 1024 * 1024 + 512 * 1024;   // 32.5 MB
    if (ws_size >= need) {
        float* opart1 = (float*)((char*)d_ws + (size_t)16 * 1024 * 1024); // [16,32)MB
        float* lpart  = (float*)((char*)d_ws + (size_t)32 * 1024 * 1024); // [32,32.5)MB
        attn_partial<<<dim3(1024), 256, 0, stream>>>(q, kp, vtp, out, opart1, lpart);
        combine<<<dim3(2048), 256, 0, stream>>>(opart1, lpart, out);
    } else {
        attn_main<<<dim3(512), 256, 0, stream>>>(q, kp, vtp, out);
    }
}

// Round 11
// 163.805 us; speedup vs baseline: 5.9879x; 5.9879x over previous
//
#include <hip/hip_runtime.h>

#define S_   4096
#define H_   1024
#define NH_  16
#define NT_  64                            // 64-key tiles
#define SCALE_LOG2E 0.18033688011112042f   // (1/8) * log2(e)

typedef __attribute__((ext_vector_type(8)))  short short8;
typedef __attribute__((ext_vector_type(16))) float f32x16;

__device__ __forceinline__ unsigned short f2bf(float x) {
    union { float f; unsigned u; } c; c.f = x;
    unsigned r = c.u + 0x7fffu + ((c.u >> 16) & 1u);   // RNE
    return (unsigned short)(r >> 16);
}
__device__ __forceinline__ unsigned pk2(float a, float b) {
    return (unsigned)f2bf(a) | ((unsigned)f2bf(b) << 16);
}
__device__ __forceinline__ unsigned pkt(float a, float b) {
    union { float f; unsigned u; } ca, cb; ca.f = a; cb.f = b;
    return __builtin_amdgcn_perm(cb.u, ca.u, 0x07060302u);  // [bf(b) : bf(a)]
}

// ---------------------------------------------------------------------------
// Prepass: fragment-major bf16 tile images, 4096 u16 per (hd,kt):
//   K''[kc][key][8] : kc = d>>3   (linear = kc*512 + key*8 + e)
//   V''[kc][d][8]   : kc = key>>3 (linear = kc*512 + d*8 + e)
// LDS transpose staging so BOTH sides are contiguous. (passing, round 5)
// ---------------------------------------------------------------------------
__global__ __launch_bounds__(256) void prepack(
    const float* __restrict__ k, const float* __restrict__ v,
    unsigned short* __restrict__ kp, unsigned short* __restrict__ vtp)
{
    __shared__ unsigned sK[64 * 33];
    __shared__ unsigned sV[64 * 33];

    const int t  = threadIdx.x;
    const int kt = blockIdx.x, hd = blockIdx.y;
    const size_t tb = ((size_t)hd * NT_ + kt) * 4096;
    uint4* gk = (uint4*)(kp + tb);
    uint4* gv = (uint4*)(vtp + tb);

    #pragma unroll
    for (int i = 0; i < 4; ++i) {
        int n   = t + 256 * i;
        int row = n >> 4, c4 = n & 15;
        size_t off = (size_t)(kt * 64 + row) * H_ + hd * 64 + c4 * 4;
        {
            float4 a = *(const float4*)(k + off);
            sK[row * 33 + c4 * 2]     = pk2(a.x, a.y);
            sK[row * 33 + c4 * 2 + 1] = pk2(a.z, a.w);
        }
        {
            float4 a = *(const float4*)(v + off);
            sV[row * 33 + c4 * 2]     = pk2(a.x, a.y);
            sV[row * 33 + c4 * 2 + 1] = pk2(a.z, a.w);
        }
    }
    __syncthreads();

    #pragma unroll
    for (int i = 0; i < 2; ++i) {
        int o = t + 256 * i;
        {   // K''
            int kc = o >> 6, key = o & 63;
            uint4 w;
            w.x = sK[key * 33 + kc * 4];
            w.y = sK[key * 33 + kc * 4 + 1];
            w.z = sK[key * 33 + kc * 4 + 2];
            w.w = sK[key * 33 + kc * 4 + 3];
            gk[o] = w;
        }
        {   // V''
            int kc = o >> 6, d = o & 63;
            int dp = d >> 1, sh = (d & 1) * 16;
            unsigned q[8];
            #pragma unroll
            for (int e = 0; e < 8; ++e)
                q[e] = (sV[(kc * 8 + e) * 33 + dp] >> sh) & 0xffffu;
            uint4 w;
            w.x = q[0] | (q[1] << 16);
            w.y = q[2] | (q[3] << 16);
            w.z = q[4] | (q[5] << 16);
            w.w = q[6] | (q[7] << 16);
            gv[o] = w;
        }
    }
}

// ---------------------------------------------------------------------------
// Main: 256 threads = 4 waves; wave (qg, kh) owns 64 qrows x 32-key half
// (s=0,1 groups share the same fragments -> 64 FLOP/byte). 512 blocks = 2
// blocks/CU. NEW vs round 5: each 16KB K''+V'' tile is staged into LDS ONCE
// per block (coalesced uint4 global loads -> ds_write), all 4 waves ds_read
// their fragments from it. Halves the block's L2 request volume (the kh/qg
// wave pairs previously each pulled duplicate fragments from L2) and
// replaces in-loop L2 latency with LDS latency. T14 split: global loads
// issued BEFORE compute, vmcnt+ds_write after; one barrier per tile
// (write-after-read protected by the previous iteration's barrier; the
// write targets the buffer compute is NOT reading). Fragment offsets are
// copied verbatim -> bit-identical math to round 5.
// ---------------------------------------------------------------------------
__global__ __launch_bounds__(256, 2) void attn_main(
    const float* __restrict__ q,
    const unsigned short* __restrict__ kp,
    const unsigned short* __restrict__ vtp,
    float* __restrict__ out)
{
    __shared__ __align__(16) unsigned short sKV[2][8192];  // [buf][K:0..4095 | V:4096..8191]
    __shared__ __align__(16) float sO[4 * 2048];           // kh=1 partials, per (qg,s)
    __shared__ float sL[2 * 128];

    const int t   = threadIdx.x;
    const int b   = blockIdx.x;
    // XCD swizzle: 2 heads per XCD (2MB of K''+V'' resident per 4MB L2)
    const int xcd = b & 7;
    const int bi  = b >> 3;                 // 0..63
    const int hd  = xcd * 2 + (bi >> 5);
    const int qt  = bi & 31;                // 32 q-tiles of 128 rows

    const int w    = t >> 6;                // 0..3
    const int lane = t & 63;
    const int l31  = lane & 31;
    const int lhi  = lane >> 5;
    const int qg   = w >> 1;                // 0..1 (64-row q group)
    const int kh   = w & 1;

    const unsigned short* gK = kp  + (size_t)hd * NT_ * 4096;
    const unsigned short* gV = vtp + (size_t)hd * NT_ * 4096;

    // ---- Q fragments (B-operand), scaled, in registers: 2 x 32-row sets ----
    short8 qf[2][4];
    #pragma unroll
    for (int s = 0; s < 2; ++s) {
        const float* qb = q + (size_t)(qt * 128 + qg * 64 + s * 32 + l31) * H_ + hd * 64 + lhi * 8;
        #pragma unroll
        for (int c = 0; c < 4; ++c) {
            float4 a  = *(const float4*)(qb + c * 16);
            float4 bb = *(const float4*)(qb + c * 16 + 4);
            union { short8 v; unsigned u[4]; } f;
            f.u[0] = pk2(a.x * SCALE_LOG2E, a.y * SCALE_LOG2E);
            f.u[1] = pk2(a.z * SCALE_LOG2E, a.w * SCALE_LOG2E);
            f.u[2] = pk2(bb.x * SCALE_LOG2E, bb.y * SCALE_LOG2E);
            f.u[3] = pk2(bb.z * SCALE_LOG2E, bb.w * SCALE_LOG2E);
            qf[s][c] = f.v;
        }
    }

    f32x16 Oacc[2][2];
    #pragma unroll
    for (int s = 0; s < 2; ++s)
        #pragma unroll
        for (int h = 0; h < 2; ++h)
            #pragma unroll
            for (int r = 0; r < 16; ++r) Oacc[s][h][r] = 0.0f;
    float2 ls[2];
    ls[0].x = 0.0f; ls[0].y = 0.0f; ls[1].x = 0.0f; ls[1].y = 0.0f;

    // loop-invariant zero C-operand
    f32x16 zero16;
    #pragma unroll
    for (int r = 0; r < 16; ++r) zero16[r] = 0.0f;

    // lane-invariant element offsets into a tile image (u16 units)
    const int kOff = (kh * 32 + l31) * 8 + lhi * 512;     // + c*1024
    const int vOff = l31 * 8 + (kh * 4 + lhi) * 512;      // + c*1024 + h*256

// ---- staging: 64B/thread, coalesced global uint4 -> LDS uint4 ----
#define STAGE_LOAD(RG, tile)                                                 \
    {                                                                        \
        const uint4* gk4 = (const uint4*)(gK + (size_t)(tile) * 4096);       \
        const uint4* gv4 = (const uint4*)(gV + (size_t)(tile) * 4096);       \
        RG[0] = gk4[t];                                                      \
        RG[1] = gk4[t + 256];                                                \
        RG[2] = gv4[t];                                                      \
        RG[3] = gv4[t + 256];                                                \
    }
#define STAGE_WRITE(RG, buf)                                                 \
    {                                                                        \
        uint4* sk4 = (uint4*)(&sKV[buf][0]);                                 \
        uint4* sv4 = (uint4*)(&sKV[buf][4096]);                              \
        sk4[t]       = RG[0];                                                \
        sk4[t + 256] = RG[1];                                                \
        sv4[t]       = RG[2];                                                \
        sv4[t + 256] = RG[3];                                                \
    }

// ---- fragment reads from the LDS tile image (offsets identical to r5) ----
#define LOADF_LDS(KF, VF, buf)                                               \
    {                                                                        \
        const unsigned short* kt_ = &sKV[buf][0] + kOff;                     \
        const unsigned short* vt_ = &sKV[buf][4096] + vOff;                  \
        KF[0] = *(const short8*)(kt_);                                       \
        KF[1] = *(const short8*)(kt_ + 1024);                                \
        KF[2] = *(const short8*)(kt_ + 2048);                                \
        KF[3] = *(const short8*)(kt_ + 3072);                                \
        VF[0] = *(const short8*)(vt_);                                       \
        VF[1] = *(const short8*)(vt_ + 256);                                 \
        VF[2] = *(const short8*)(vt_ + 1024);                                \
        VF[3] = *(const short8*)(vt_ + 1280);                                \
    }

#define SMAX(ST, LS, PU)                                                     \
    {                                                                        \
        _Pragma("unroll")                                                    \
        for (int i2_ = 0; i2_ < 8; ++i2_) {                                  \
            float p0 = __builtin_amdgcn_exp2f(ST[2 * i2_]);                  \
            float p1 = __builtin_amdgcn_exp2f(ST[2 * i2_ + 1]);              \
            LS.x += p0; LS.y += p1;                                          \
            PU[i2_] = pkt(p0, p1);                                           \
        }                                                                    \
    }

#define PVAC(PU, VF, OA)                                                     \
    {                                                                        \
        _Pragma("unroll")                                                    \
        for (int c_ = 0; c_ < 2; ++c_) {                                     \
            unsigned a0 = PU[4 * c_],     b0 = PU[4 * c_ + 2];               \
            unsigned a1 = PU[4 * c_ + 1], b1 = PU[4 * c_ + 3];               \
            asm("v_permlane32_swap_b32 %0, %1" : "+v"(a0), "+v"(b0));        \
            asm("v_permlane32_swap_b32 %0, %1" : "+v"(a1), "+v"(b1));        \
            union { short8 v; unsigned u[4]; } pf;                           \
            pf.u[0] = a0; pf.u[1] = a1; pf.u[2] = b0; pf.u[3] = b1;          \
            OA[0] = __builtin_amdgcn_mfma_f32_32x32x16_bf16(pf.v, VF[2 * c_],     OA[0], 0, 0, 0); \
            OA[1] = __builtin_amdgcn_mfma_f32_32x32x16_bf16(pf.v, VF[2 * c_ + 1], OA[1], 0, 0, 0); \
        }                                                                    \
    }

#define COMPUTE(KF, VF)                                                      \
    {                                                                        \
        f32x16 st0 = __builtin_amdgcn_mfma_f32_32x32x16_bf16(KF[0], qf[0][0], zero16, 0, 0, 0); \
        f32x16 st1 = __builtin_amdgcn_mfma_f32_32x32x16_bf16(KF[0], qf[1][0], zero16, 0, 0, 0); \
        st0 = __builtin_amdgcn_mfma_f32_32x32x16_bf16(KF[1], qf[0][1], st0, 0, 0, 0); \
        st1 = __builtin_amdgcn_mfma_f32_32x32x16_bf16(KF[1], qf[1][1], st1, 0, 0, 0); \
        st0 = __builtin_amdgcn_mfma_f32_32x32x16_bf16(KF[2], qf[0][2], st0, 0, 0, 0); \
        st1 = __builtin_amdgcn_mfma_f32_32x32x16_bf16(KF[2], qf[1][2], st1, 0, 0, 0); \
        st0 = __builtin_amdgcn_mfma_f32_32x32x16_bf16(KF[3], qf[0][3], st0, 0, 0, 0); \
        st1 = __builtin_amdgcn_mfma_f32_32x32x16_bf16(KF[3], qf[1][3], st1, 0, 0, 0); \
        unsigned pu0[8], pu1[8];                                             \
        SMAX(st0, ls[0], pu0);                                               \
        PVAC(pu0, VF, Oacc[0]);                                              \
        SMAX(st1, ls[1], pu1);                                               \
        PVAC(pu1, VF, Oacc[1]);                                              \
    }

    // ---- K-loop: LDS double-buffer, one barrier/tile, T14 load/write split ----
    uint4 rg[4];
    STAGE_LOAD(rg, 0);
    STAGE_WRITE(rg, 0);
    __syncthreads();
    for (int kt = 0; kt < NT_; ++kt) {
        const int cur = kt & 1;
        if (kt < NT_ - 1) STAGE_LOAD(rg, kt + 1);   // issue early (hides under compute)
        short8 kf[4], vf[4];
        LOADF_LDS(kf, vf, cur);
        COMPUTE(kf, vf);
        if (kt < NT_ - 1) STAGE_WRITE(rg, cur ^ 1); // other buffer; prev barrier protects
        __syncthreads();
    }

#undef STAGE_LOAD
#undef STAGE_WRITE
#undef LOADF_LDS
#undef SMAX
#undef PVAC
#undef COMPUTE

    // ---- epilogue: combine kh halves, normalize, store ----
    #pragma unroll
    for (int s = 0; s < 2; ++s) {
        float lsum = ls[s].x + ls[s].y;
        lsum += __shfl_xor(lsum, 32);
        if (lhi == 0) sL[kh * 128 + qg * 64 + s * 32 + l31] = lsum;
    }
    if (kh == 1) {
        #pragma unroll
        for (int s = 0; s < 2; ++s) {
            float* o = sO + (qg * 2 + s) * 2048;
            #pragma unroll
            for (int h = 0; h < 2; ++h)
                #pragma unroll
                for (int r = 0; r < 16; ++r)
                    o[h * 1024 + r * 64 + lane] = Oacc[s][h][r];
        }
    }
    __syncthreads();
    if (kh == 0) {
        #pragma unroll
        for (int s = 0; s < 2; ++s) {
            float linv[4][4];
            #pragma unroll
            for (int qd = 0; qd < 4; ++qd) {
                int base = qg * 64 + s * 32 + 8 * qd + 4 * lhi;
                float4 a  = *(const float4*)(sL + base);
                float4 bb = *(const float4*)(sL + 128 + base);
                linv[qd][0] = __builtin_amdgcn_rcpf(a.x + bb.x);
                linv[qd][1] = __builtin_amdgcn_rcpf(a.y + bb.y);
                linv[qd][2] = __builtin_amdgcn_rcpf(a.z + bb.z);
                linv[qd][3] = __builtin_amdgcn_rcpf(a.w + bb.w);
            }
            const float* o = sO + (qg * 2 + s) * 2048;
            #pragma unroll
            for (int h = 0; h < 2; ++h)
                #pragma unroll
                for (int qd = 0; qd < 4; ++qd)
                    #pragma unroll
                    for (int e = 0; e < 4; ++e) {
                        int r   = 4 * qd + e;
                        int row = e + 8 * qd + 4 * lhi;
                        float val = (Oacc[s][h][r] + o[h * 1024 + r * 64 + lane]) * linv[qd][e];
                        out[(size_t)(qt * 128 + qg * 64 + s * 32 + row) * H_ + hd * 64 + h * 32 + l31] = val;
                    }
        }
    }
}

extern "C" void kernel_launch(void* const* d_in, const int* in_sizes, int n_in,
                              void* d_out, int out_size, void* d_ws, size_t ws_size,
                              hipStream_t stream) {
    const float* q = (const float*)d_in[0];
    const float* k = (const float*)d_in[1];
    const float* v = (const float*)d_in[2];
    float* out = (float*)d_out;

    unsigned short* kp  = (unsigned short*)d_ws;                 // [0, 8MB)
    unsigned short* vtp = kp + (size_t)NH_ * NT_ * 4096;         // [8MB, 16MB)

    prepack<<<dim3(NT_, NH_), 256, 0, stream>>>(k, v, kp, vtp);
    attn_main<<<dim3(512), 256, 0, stream>>>(q, kp, vtp, out);
}